// Round 14
// baseline (848.138 us; speedup 1.0000x reference)
//
#include <hip/hip_runtime.h>
#include <math.h>

// LVCBlock forward, MI355X (gfx950).
// Shapes: B=16, CIN=32, CCOND=100, Lc=512, HOP=8, T=4096, HID=64, NL=4, K=3, COUT=64.
// ALL inputs and the output are float32.
//
// R28 vs R27 (825.2us == R21 within noise; single-buffer kc null because grid
// 1024 = 4 blocks/CU exactly — but it frees a 5th 32KB LDS slot + 16 wave
// slots per CU during k_lvc):
//  (1) k_lvcP: k_lvc blocks [0,1024) (R27 single-buffer body, 32KB LDS) +
//      EMBEDDED pack(L+1) [1024,1601) + head(L+1) [1601,2113) — zero-LDS
//      latency-bound work that fills the free 5th block slot and runs inside
//      k_lvc's ~122us shadow. pack/head depend only on ker_w/hp, NOT on
//      k_lvc(L)'s xx output -> safe concurrency.
//  (2) Whi/Wlo/Bpk/kbL double-buffered by layer parity: k_lvc(L) reads
//      buf[L&1] while embedded writers fill buf[(L+1)&1]. No overlap.
//  (3) Per-layer tail shrinks to cblock-only k_cb (1024 blocks) for L>=1;
//      L=0 uses the full R21 trio. Needs 26.35MB ws (runtime check; R27-exact
//      fallback otherwise — R25's timing proves >=33.7MB available).
// All bodies byte-identical to absmax-proven versions. absmax 0.03125.

#define DEV __device__ __forceinline__

typedef unsigned short ushort;
typedef unsigned int uint;
typedef __attribute__((ext_vector_type(8))) short short8;   // 8 bf16 (4 VGPRs)
typedef __attribute__((ext_vector_type(4))) float f32x4;
typedef __attribute__((ext_vector_type(2))) float f32x2;

DEV float lrelu(float x) { return x > 0.f ? x : 0.2f * x; }

DEV ushort f2bf(float f) {                     // fp32 -> bf16 bits, RNE
    uint u = __float_as_uint(f);
    return (ushort)((u + 0x7fffu + ((u >> 16) & 1u)) >> 16);
}
DEV float bf2f(ushort b) { return __uint_as_float(((uint)b) << 16); }

// ---------------- kernel predictor input conv body (100->64, k=5, pad=2) + lrelu
DEV void pred_body(int idx, const float* __restrict__ c, const float* __restrict__ w,
                   const float* __restrict__ bias, float* __restrict__ hp) {
    int l4 = idx & 127, co = (idx >> 7) & 63, b = idx >> 13;
    int l0 = l4 << 2;
    float a0, a1, a2, a3;
    a0 = a1 = a2 = a3 = bias[co];
    for (int ci = 0; ci < 100; ++ci) {
        const float* crow = c + (b * 100 + ci) * 512;
        const float* wrow = w + (co * 100 + ci) * 5;
        float f0, f1, f2, f3, f4, f5, f6, f7;          // p = l0-2 .. l0+5
        if (l0 == 0) {
            float2 pb = *(const float2*)(crow + 0);
            float2 pc = *(const float2*)(crow + 2);
            float2 pd = *(const float2*)(crow + 4);
            f0 = 0.f; f1 = 0.f;
            f2 = pb.x; f3 = pb.y; f4 = pc.x; f5 = pc.y; f6 = pd.x; f7 = pd.y;
        } else if (l0 == 508) {
            float2 pa = *(const float2*)(crow + 506);
            float2 pb = *(const float2*)(crow + 508);
            float2 pc = *(const float2*)(crow + 510);
            f0 = pa.x; f1 = pa.y; f2 = pb.x; f3 = pb.y; f4 = pc.x; f5 = pc.y;
            f6 = 0.f; f7 = 0.f;
        } else {
            float2 pa = *(const float2*)(crow + l0 - 2);
            float2 pb = *(const float2*)(crow + l0);
            float2 pc = *(const float2*)(crow + l0 + 2);
            float2 pd = *(const float2*)(crow + l0 + 4);
            f0 = pa.x; f1 = pa.y; f2 = pb.x; f3 = pb.y; f4 = pc.x; f5 = pc.y;
            f6 = pd.x; f7 = pd.y;
        }
        float w0 = wrow[0], w1 = wrow[1], w2 = wrow[2], w3 = wrow[3], w4 = wrow[4];
        a0 += f0 * w0; a0 += f1 * w1; a0 += f2 * w2; a0 += f3 * w3; a0 += f4 * w4;
        a1 += f1 * w0; a1 += f2 * w1; a1 += f3 * w2; a1 += f4 * w3; a1 += f5 * w4;
        a2 += f2 * w0; a2 += f3 * w1; a2 += f4 * w2; a2 += f5 * w3; a2 += f6 * w4;
        a3 += f3 * w0; a3 += f4 * w1; a3 += f5 * w2; a3 += f6 * w3; a3 += f7 * w4;
    }
    float* hrow = hp + (size_t)(b * 64 + co) * 520 + 4 + l0;
    hrow[0] = lrelu(a0); hrow[1] = lrelu(a1); hrow[2] = lrelu(a2); hrow[3] = lrelu(a3);
    if (l0 == 0) hrow[-1] = 0.f;            // pad zeros (ws re-poisoned each call)
    if (l0 == 508) hrow[4] = 0.f;
}

// ---------------- convt_pre body: lrelu then ConvTranspose1d(32->32, k=16, s=8, p=4)
DEV void convt_body(int relblk, int s, const float* __restrict__ x,
                    const float* __restrict__ w, const float* __restrict__ bias,
                    float* __restrict__ xx) {
    int co = relblk & 31, b = relblk >> 5;
    float acc[8];
    float bz = bias[co];
#pragma unroll
    for (int m = 0; m < 8; ++m) acc[m] = bz;
    for (int ci = 0; ci < 32; ++ci) {
        const float* xr = x + (b * 32 + ci) * 512;
        float a = (s < 512) ? lrelu(xr[s]) : 0.f;      // FMA-with-0 == skip, exact
        float p = (s >= 1) ? lrelu(xr[s - 1]) : 0.f;
        const float* wr = w + (ci * 32 + co) * 16;
        float4 q0 = *(const float4*)(wr);
        float4 q1 = *(const float4*)(wr + 4);
        float4 q2 = *(const float4*)(wr + 8);
        float4 q3 = *(const float4*)(wr + 12);
        float wgt[16] = {q0.x, q0.y, q0.z, q0.w, q1.x, q1.y, q1.z, q1.w,
                         q2.x, q2.y, q2.z, q2.w, q3.x, q3.y, q3.z, q3.w};
#pragma unroll
        for (int m = 0; m < 8; ++m) {
            acc[m] += a * wgt[m];                      // s0 term first (orig order)
            acc[m] += p * wgt[m + 8];                  // then s0-1 term
        }
    }
    int t0 = 8 * s - 4;
    float* xrow = xx + (size_t)(b * 32 + co) * 4096;
    if (s >= 1 && s < 512) {
#pragma unroll
        for (int m = 0; m < 8; m += 2)
            *(float2*)(xrow + t0 + m) = make_float2(acc[m], acc[m + 1]);
    } else {
#pragma unroll
        for (int m = 0; m < 8; ++m) {
            int t = t0 + m;
            if (t >= 0 && t < 4096) xrow[t] = acc[m];
        }
    }
}

// ---------------- fused prologue: pred_in (blocks [0,228)) || convt ([228,740))
__global__ __launch_bounds__(576) void
k_fused_pc(const float* __restrict__ c, const float* __restrict__ in_w,
           const float* __restrict__ in_b, float* __restrict__ hp,
           const float* __restrict__ x, const float* __restrict__ ct_w,
           const float* __restrict__ ct_b, float* __restrict__ xx) {
    int blk = blockIdx.x;
    if (blk < 228) {
        int idx = blk * 576 + threadIdx.x;
        if (idx < 131072) pred_body(idx, c, in_w, in_b, hp);
    } else {
        int s = threadIdx.x;
        if (s <= 512) convt_body(blk - 228, s, x, ct_w, ct_b, xx);
    }
}

// ---------------- residual conv (64->64, k=3, pad=1) + lrelu, optional accumulate
__global__ void k_res(const float* __restrict__ src, const float* __restrict__ w,
                      const float* __restrict__ bias, float* __restrict__ dst,
                      const float* __restrict__ accum) {
    int idx = blockIdx.x * 256 + threadIdx.x;          // 16*64*128
    int l4 = idx & 127, co = (idx >> 7) & 63, b = idx >> 13;
    int l0 = l4 << 2;
    float a0, a1, a2, a3;
    a0 = a1 = a2 = a3 = bias[co];
    for (int ci = 0; ci < 64; ++ci) {
        const float* row = src + (size_t)(b * 64 + ci) * 520 + 4;
        float e0 = row[l0 - 1];
        float2 m01 = *(const float2*)(row + l0);
        float2 m23 = *(const float2*)(row + l0 + 2);
        float e1 = row[l0 + 4];
        const float* wr = w + (co * 64 + ci) * 3;
        float w0 = wr[0], w1 = wr[1], w2 = wr[2];
        a0 += e0 * w0;    a0 += m01.x * w1; a0 += m01.y * w2;
        a1 += m01.x * w0; a1 += m01.y * w1; a1 += m23.x * w2;
        a2 += m01.y * w0; a2 += m23.x * w1; a2 += m23.y * w2;
        a3 += m23.x * w0; a3 += m23.y * w1; a3 += e1 * w2;
    }
    float v0 = lrelu(a0), v1 = lrelu(a1), v2 = lrelu(a2), v3 = lrelu(a3);
    size_t rb = (size_t)(b * 64 + co) * 520 + 4 + l0;
    if (accum) {
        const float* ar = accum + rb;
        v0 += ar[0]; v1 += ar[1]; v2 += ar[2]; v3 += ar[3];
    }
    float* dr = dst + rb;
    dr[0] = v0; dr[1] = v1; dr[2] = v2; dr[3] = v3;
    if (l0 == 0) dr[-1] = 0.f;
    if (l0 == 508) dr[4] = 0.f;
}

// ---------------- bias head body, ONE layer's 64 channels (k=3, pad=1)
DEV void head_body(int idx, const float* __restrict__ hp, const float* __restrict__ w,
                   const float* __restrict__ bias, float* __restrict__ out, int layer) {
    int l4 = idx & 127, o = (idx >> 7) & 63, b = idx >> 13;
    int l0 = l4 << 2;
    int ch = layer * 64 + o;
    float a0, a1, a2, a3;
    a0 = a1 = a2 = a3 = bias[ch];
    for (int ci = 0; ci < 64; ++ci) {
        const float* row = hp + (size_t)(b * 64 + ci) * 520 + 4;
        float e0 = row[l0 - 1];
        float2 m01 = *(const float2*)(row + l0);
        float2 m23 = *(const float2*)(row + l0 + 2);
        float e1 = row[l0 + 4];
        const float* wr = w + (ch * 64 + ci) * 3;
        float w0 = wr[0], w1 = wr[1], w2 = wr[2];
        a0 += e0 * w0;    a0 += m01.x * w1; a0 += m01.y * w2;
        a1 += m01.x * w0; a1 += m01.y * w1; a1 += m23.x * w2;
        a2 += m01.y * w0; a2 += m23.x * w1; a2 += m23.y * w2;
        a3 += m23.x * w0; a3 += m23.y * w1; a3 += e1 * w2;
    }
    float* orow = out + (size_t)(b * 64 + o) * 512 + l0;
    orow[0] = a0; orow[1] = a1; orow[2] = a2; orow[3] = a3;
}

// ---------------- pack body (ONE layer), INVERSE mapping: idx=(ch, 8-col grp).
// Coalesced 2xfloat4 reads; scattered uint4 writes. relblk 576 = bias.
DEV void pack_dev(int relblk, int tid, const float* __restrict__ ker_w,
                  const float* __restrict__ ker_b, ushort* __restrict__ WhiB,
                  ushort* __restrict__ WloB, float* __restrict__ BpkB, int layer) {
    if (relblk == 576) {                // bias pack: 6144 entries
        for (int idx = tid; idx < 6144; idx += 256) {
            int c = idx / 384, r = idx - c * 384;
            int ik = r >> 2, oc = r & 3;
            int i = ik / 3, kk = ik - i * 3;
            int o = 32 * (oc & 1) + 2 * c + (oc >> 1);
            BpkB[idx] = ker_b[layer * 6144 + (i * 64 + o) * 3 + kk];
        }
        return;
    }
    int idx = relblk * 256 + tid;                      // < 147456 = 6144 ch * 24 cg
    int cg = idx % 24, ch = idx / 24;
    int q3 = ch / 3, kk = ch - q3 * 3;                 // ch = (i*64+o)*3 + kk
    int o = q3 & 63, i = q3 >> 6;
    int oc = ((o & 1) << 1) | (o >> 5);                // o = 32*(oc&1) + 2c + (oc>>1)
    int c = (o & 31) >> 1;
    int r = (i * 3 + kk) * 4 + oc;                     // r = ik*4 + oc
    int mt = r >> 4, m = r & 15;
    int ks = cg >> 2, quad = cg & 3;                   // col = ks*32 + quad*8 + j
    const float* src = ker_w + ((size_t)(layer * 6144 + ch)) * 192 + cg * 8;
    float4 fa = *(const float4*)(src);
    float4 fb = *(const float4*)(src + 4);
    float f[8] = {fa.x, fa.y, fa.z, fa.w, fb.x, fb.y, fb.z, fb.w};
    uint uh[4], ul[4];
#pragma unroll
    for (int t = 0; t < 4; ++t) {
        float f0 = f[2 * t], f1 = f[2 * t + 1];
        ushort h0 = f2bf(f0), h1 = f2bf(f1);
        ushort l0 = f2bf(f0 - bf2f(h0)), l1 = f2bf(f1 - bf2f(h1));
        uh[t] = (uint)h0 | ((uint)h1 << 16);
        ul[t] = (uint)l0 | ((uint)l1 << 16);
    }
    size_t base = ((size_t)((c * 24 + mt) * 6 + ks) * 64 + quad * 16 + m) * 8;
    *reinterpret_cast<uint4*>(WhiB + base) = make_uint4(uh[0], uh[1], uh[2], uh[3]);
    *reinterpret_cast<uint4*>(WloB + base) = make_uint4(ul[0], ul[1], ul[2], ul[3]);
}

// ---------------- dilated conv block body, LDS-staged -> PADDED cb (stride 4104)
template <int D>
DEV void cblock2_body(int blk, int tid, const float* __restrict__ xx,
                      const float* __restrict__ w, const float* __restrict__ bias,
                      float* __restrict__ cbp, int layer,
                      float (*lx)[132], float (*wl)[100]) {
    int tt = blk & 63, b = blk >> 6;                   // 1024 rel blocks
    int W0 = tt * 64 - 28;

    {
        int r = tid >> 3, cg = (tid & 7) * 16;
        const float* srow = xx + (size_t)(b * 32 + r) * 4096 + W0 + cg;
        float* drow = &lx[r][cg];
        if (tt > 0 && tt < 63) {                       // fully interior: vector
#pragma unroll
            for (int q = 0; q < 4; ++q) {
                float4 v = *(const float4*)(srow + q * 4);
                drow[q * 4 + 0] = lrelu(v.x); drow[q * 4 + 1] = lrelu(v.y);
                drow[q * 4 + 2] = lrelu(v.z); drow[q * 4 + 3] = lrelu(v.w);
            }
        } else {                                       // edge tiles: guarded
#pragma unroll
            for (int j = 0; j < 16; ++j) {
                int p = W0 + cg + j;
                drow[j] = (p >= 0 && p < 4096) ? lrelu(srow[j]) : 0.f;
            }
        }
    }
    for (int f = tid; f < 3072; f += 256)
        wl[f / 96][f % 96] = w[layer * 3072 + f];
    __syncthreads();

    int ci = tid >> 3, ug = tid & 7;
    int t0 = tt * 64 + ug * 8;
    int lb = ug * 8 + 28;
    float acc[8];
    float bz = bias[layer * 32 + ci];
#pragma unroll
    for (int u = 0; u < 8; ++u) acc[u] = bz;
    const float* Wr = &wl[ci][0];
    const float* Lb = &lx[0][lb];
    for (int c2 = 0; c2 < 32; ++c2) {
        float w0 = Wr[c2 * 3], w1 = Wr[c2 * 3 + 1], w2 = Wr[c2 * 3 + 2];
        const float* Lr = Lb + c2 * 132;
#pragma unroll
        for (int u = 0; u < 8; ++u) {
            float v0 = Lr[u - D], v1 = Lr[u], v2 = Lr[u + D];
            acc[u] += v0 * w0; acc[u] += v1 * w1; acc[u] += v2 * w2;
        }
    }
    float* crow = cbp + (size_t)(b * 32 + ci) * 4104 + 4 + t0;
#pragma unroll
    for (int u = 0; u < 8; u += 2)
        *(float2*)(crow + u) = make_float2(lrelu(acc[u]), lrelu(acc[u + 1]));
    if (t0 == 0) crow[-1] = 0.f;        // guard cells for k_lvc phase-2
    if (t0 == 4088) crow[8] = 0.f;      // data[4096]
}

// ---------------- cblock-only kernel (per-layer, batched path L>=1)
template <int D>
__global__ __launch_bounds__(256) void
k_cb(const float* __restrict__ xx, const float* __restrict__ cb_ws,
     const float* __restrict__ cb_bs, float* __restrict__ cbp, int layer) {
    __shared__ float lx[32][132];
    __shared__ float wl[32][100];
    cblock2_body<D>(blockIdx.x, threadIdx.x, xx, cb_ws, cb_bs, cbp, layer, lx, wl);
}

// ---------------- per-layer trio (R21-exact): cblock2 [0,1024) || pack
// [1024,1601) || head [1601,2113). Used for L=0 (and fallback all layers).
template <int D>
__global__ __launch_bounds__(256) void
k_trio(const float* __restrict__ xx, const float* __restrict__ cb_ws,
       const float* __restrict__ cb_bs, float* __restrict__ cbp,
       const float* __restrict__ ker_w, const float* __restrict__ ker_b,
       ushort* __restrict__ Whi, ushort* __restrict__ Wlo, float* __restrict__ Bpk,
       const float* __restrict__ hp, const float* __restrict__ bias_w,
       const float* __restrict__ bias_b, float* __restrict__ kbL, int layer) {
    __shared__ float lx[32][132];
    __shared__ float wl[32][100];
    int blk = blockIdx.x;
    if (blk < 1024) {
        cblock2_body<D>(blk, threadIdx.x, xx, cb_ws, cb_bs, cbp, layer, lx, wl);
    } else if (blk < 1601) {
        pack_dev(blk - 1024, threadIdx.x, ker_w, ker_b, Whi, Wlo, Bpk, layer);
    } else {
        head_body((blk - 1601) * 256 + threadIdx.x, hp, bias_w, bias_b, kbL, layer);
    }
}

// ---------------- k_lvcP: blocks [0,1024) = R27 single-buffer k_lvc (32KB LDS,
// proven 122us, absmax-proven); [1024,1601) = pack(layerN) -> parity buffers;
// [1601,2113) = head(layerN). Embedded blocks are zero-LDS-use latency work
// filling the free 5th block slot per CU. Launch grid 1024 to disable embed.
__global__ __launch_bounds__(256) void
k_lvcP(const float* __restrict__ h, const float* __restrict__ cbp,
       const float* __restrict__ kbL, const ushort* __restrict__ Whi,
       const ushort* __restrict__ Wlo, const float* __restrict__ Bpk,
       float* __restrict__ xx,
       const float* __restrict__ ker_w, const float* __restrict__ ker_b,
       ushort* __restrict__ WhiN, ushort* __restrict__ WloN,
       float* __restrict__ BpkN, float* __restrict__ kbLN,
       const float* __restrict__ bias_w, const float* __restrict__ bias_b,
       int layerN) {
    __shared__ ushort HfH[6144];        // 12288 B
    __shared__ ushort HfL[6144];        // 12288 B
    __shared__ float kc[2048];          // 8192 B single buffer
    // total 32768 B -> 5 blocks/CU; k_lvc grid-slice is 1024 = 4/CU

    if (blockIdx.x >= 1024) {           // ---- embedded pack/head for layerN
        int blk = blockIdx.x;
        if (blk < 1601) {
            pack_dev(blk - 1024, threadIdx.x, ker_w, ker_b, WhiN, WloN, BpkN, layerN);
        } else {
            head_body((blk - 1601) * 256 + threadIdx.x, h, bias_w, bias_b, kbLN, layerN);
        }
        return;
    }

    int tid = threadIdx.x;
    // bijective remap within the 1024-block slice: XCD = blockIdx%8 shared by
    // the 4 qtr of group g -> one (b,lt) cbp/h window per XCD.
    int g = (blockIdx.x >> 5) * 8 + (blockIdx.x & 7);   // (b,lt) group in [0,256)
    int qtr = (blockIdx.x >> 3) & 3;
    int lt = g & 15;
    int b = g >> 4;
    int l0 = lt * 32;

    // ---- build h hi/lo B-fragments ONCE into LDS (flat fragment order).
    for (int v = tid; v < 6144; v += 256) {
        int j = v & 7;
        int lane_ = (v >> 3) & 63;
        int r2 = v >> 9;                // nt_*6 + ks
        int ks = r2 % 6, nt_ = r2 / 6;
        int n = nt_ * 16 + (lane_ & 15);
        int cj = ks * 32 + (lane_ >> 4) * 8 + j;
        int ci = cj / 3, jt = cj - ci * 3;
        int p = l0 + n + jt - 1;
        float val = h[(size_t)(b * 64 + ci) * 520 + 4 + p];   // padded, p in [-1,512]
        ushort hi = f2bf(val);
        HfH[v] = hi;
        HfL[v] = f2bf(val - bf2f(hi));
    }
    __syncthreads();

    int wave = tid >> 6, lane = tid & 63;
    int n16 = lane & 15, quad = lane >> 4;
    int nt = wave & 1;                  // this wave's n-tile
    int mt0 = (wave >> 1) * 2;          // this wave's 2 local m-tiles

    const ushort* hfh = &HfH[(nt * 6) * 512 + lane * 8];
    const ushort* hfl = &HfL[(nt * 6) * 512 + lane * 8];

    int h8 = tid & 7, n2 = tid >> 3;    // phase-2: hop h8, location n2 in [0,32)
    int lg = l0 + n2;
    int tglob = lg * 8 + h8;
    const float* cbb = cbp + (size_t)b * 32 * 4104;
    const float* kbb = kbL + b * 64 * 512;
    float* xxb = xx + b * 32 * 4096;

    for (int cc = 0; cc < 4; ++cc) {
        int c = qtr * 4 + cc;
        f32x2 A01 = {0.f, 0.f}, A23 = {0.f, 0.f};       // phase-2 partials (a0,a1),(a2,a3)
        for (int p = 0; p < 6; ++p) {
            // ---- phase 1: 2 MT jobs per wave, shared h fragments; weights
            // direct from global (b128 coalesced, L2-resident quarter slice).
            {
                int MT0 = p * 4 + mt0;
                const ushort* wh0 = Whi + (((size_t)(c * 24 + MT0) * 6) * 64 + lane) * 8;
                const ushort* wl0 = Wlo + (((size_t)(c * 24 + MT0) * 6) * 64 + lane) * 8;
                f32x4 acc0 = {0.f, 0.f, 0.f, 0.f};
                f32x4 acc1 = {0.f, 0.f, 0.f, 0.f};
                __builtin_amdgcn_s_setprio(1);
#pragma unroll 2
                for (int ks = 0; ks < 6; ++ks) {
                    short8 bhf = *reinterpret_cast<const short8*>(hfh + ks * 512);
                    short8 blf = *reinterpret_cast<const short8*>(hfl + ks * 512);
                    short8 w0h = *reinterpret_cast<const short8*>(wh0 + ks * 512);
                    short8 w0l = *reinterpret_cast<const short8*>(wl0 + ks * 512);
                    acc0 = __builtin_amdgcn_mfma_f32_16x16x32_bf16(w0h, bhf, acc0, 0, 0, 0);
                    acc0 = __builtin_amdgcn_mfma_f32_16x16x32_bf16(w0l, bhf, acc0, 0, 0, 0);
                    acc0 = __builtin_amdgcn_mfma_f32_16x16x32_bf16(w0h, blf, acc0, 0, 0, 0);
                    short8 w1h = *reinterpret_cast<const short8*>(wh0 + 3072 + ks * 512);
                    short8 w1l = *reinterpret_cast<const short8*>(wl0 + 3072 + ks * 512);
                    acc1 = __builtin_amdgcn_mfma_f32_16x16x32_bf16(w1h, bhf, acc1, 0, 0, 0);
                    acc1 = __builtin_amdgcn_mfma_f32_16x16x32_bf16(w1l, bhf, acc1, 0, 0, 0);
                    acc1 = __builtin_amdgcn_mfma_f32_16x16x32_bf16(w1h, blf, acc1, 0, 0, 0);
                }
                __builtin_amdgcn_s_setprio(0);
                acc0 += *reinterpret_cast<const f32x4*>(Bpk + c * 384 + MT0 * 16 + quad * 4);
                acc1 += *reinterpret_cast<const f32x4*>(Bpk + c * 384 + (MT0 + 1) * 16 + quad * 4);
                // D: col=lane&15 -> n16, row=quad*4+reg; ik_local = lmt*4+quad, oc=reg
                *reinterpret_cast<f32x4*>(
                    &kc[((mt0 * 4 + quad) * 32 + nt * 16 + n16) * 4]) = acc0;
                *reinterpret_cast<f32x4*>(
                    &kc[(((mt0 + 1) * 4 + quad) * 32 + nt * 16 + n16) * 4]) = acc1;
            }
            __syncthreads();            // kc(p) complete

            // ---- phase 2 partial: global ik = p*16 + ikk (ascending; padded cb)
#pragma unroll
            for (int ikk = 0; ikk < 16; ++ikk) {
                int ik = p * 16 + ikk;
                int i = ik / 3, kk = ik - i * 3;
                float xv = cbb[(size_t)i * 4104 + 3 + tglob + kk];
                float4 kv = *reinterpret_cast<const float4*>(&kc[(ikk * 32 + n2) * 4]);
                f32x2 xv2 = {xv, xv};
                f32x2 klo = {kv.x, kv.y};
                f32x2 khi = {kv.z, kv.w};
                A01 = __builtin_elementwise_fma(klo, xv2, A01);
                A23 = __builtin_elementwise_fma(khi, xv2, A23);
            }
            __syncthreads();            // kc consumed; next phase-1 may overwrite
        }
        // ---- gate: oc {0,1,2,3} -> o {2c, 32+2c, 2c+1, 32+2c+1}
        {
            float pa = A01.x + kbb[(2 * c) * 512 + lg];
            float pb = A01.y + kbb[(32 + 2 * c) * 512 + lg];
            float g2 = (1.f / (1.f + expf(-pa))) * tanhf(pb);
            xxb[(2 * c) * 4096 + tglob] += g2;
            pa = A23.x + kbb[(2 * c + 1) * 512 + lg];
            pb = A23.y + kbb[(32 + 2 * c + 1) * 512 + lg];
            g2 = (1.f / (1.f + expf(-pa))) * tanhf(pb);
            xxb[(2 * c + 1) * 4096 + tglob] += g2;
        }
    }
}

extern "C" void kernel_launch(void* const* d_in, const int* in_sizes, int n_in,
                              void* d_out, int out_size, void* d_ws, size_t ws_size,
                              hipStream_t stream) {
    const float* x      = (const float*)d_in[0];
    const float* c      = (const float*)d_in[1];
    const float* in_w   = (const float*)d_in[2];
    const float* in_b   = (const float*)d_in[3];
    const float* res_ws = (const float*)d_in[4];
    const float* res_bs = (const float*)d_in[5];
    const float* ker_w  = (const float*)d_in[6];
    const float* ker_b  = (const float*)d_in[7];
    const float* bias_w = (const float*)d_in[8];
    const float* bias_b = (const float*)d_in[9];
    const float* ct_w   = (const float*)d_in[10];
    const float* ct_b   = (const float*)d_in[11];
    const float* cb_ws  = (const float*)d_in[12];
    const float* cb_bs  = (const float*)d_in[13];

    float* ws = (float*)d_ws;
    float* xx = (float*)d_out;                 // state tensor lives in d_out

    // Batched (parity) layout: 6586368 floats = 26.35 MB
    const size_t NEED = 6586368ull * 4ull;
    bool batched = (ws_size >= NEED);

    float* hp, *tmp, *cbp;
    float* kbLp[2]; ushort* Whip[2]; ushort* Wlop[2]; float* Bpkp[2];
    if (batched) {
        hp      = ws;                          // 532480
        tmp     = ws + 532480;                 // 532480
        kbLp[0] = ws + 1064960;                // 524288
        kbLp[1] = ws + 1589248;                // 524288
        cbp     = ws + 2113536;                // 2101248
        Whip[0] = (ushort*)(ws + 4214784);     // 589824 floats each
        Wlop[0] = (ushort*)(ws + 4804608);
        Whip[1] = (ushort*)(ws + 5394432);
        Wlop[1] = (ushort*)(ws + 5984256);
        Bpkp[0] = ws + 6574080;                // 6144
        Bpkp[1] = ws + 6580224;                // 6144
    } else {
        hp      = ws;                          // R21 layout (19.51 MB)
        kbLp[0] = ws + 532480;  kbLp[1] = kbLp[0];
        tmp     = ws + 1056768;
        cbp     = ws + 1589248;
        Whip[0] = (ushort*)(ws + 3690496);  Whip[1] = Whip[0];
        Wlop[0] = (ushort*)(ws + 4280320);  Wlop[1] = Wlop[0];
        Bpkp[0] = ws + 4870144;  Bpkp[1] = Bpkp[0];
    }

    k_fused_pc<<<740, 576, 0, stream>>>(c, in_w, in_b, hp, x, ct_w, ct_b, xx);
    for (int j = 0; j < 3; ++j) {
        k_res<<<512, 256, 0, stream>>>(hp,  res_ws + (j * 2 + 0) * 64 * 64 * 3,
                                       res_bs + (j * 2 + 0) * 64, tmp, nullptr);
        k_res<<<512, 256, 0, stream>>>(tmp, res_ws + (j * 2 + 1) * 64 * 64 * 3,
                                       res_bs + (j * 2 + 1) * 64, hp, hp);
    }

    if (batched) {
        // L=0: full trio into parity-0 buffers.
        k_trio<1><<<2113, 256, 0, stream>>>(xx, cb_ws, cb_bs, cbp,
            ker_w, ker_b, Whip[0], Wlop[0], Bpkp[0], hp, bias_w, bias_b, kbLp[0], 0);
        for (int L = 0; L < 4; ++L) {
            int pr = L & 1, pn = (L + 1) & 1;
            int grid = (L < 3) ? 2113 : 1024;      // embed pack/head(L+1) for L<3
            k_lvcP<<<grid, 256, 0, stream>>>(hp, cbp, kbLp[pr],
                Whip[pr], Wlop[pr], Bpkp[pr], xx,
                ker_w, ker_b, Whip[pn], Wlop[pn], Bpkp[pn], kbLp[pn],
                bias_w, bias_b, L + 1);
            if (L < 3) {
                switch (L + 1) {
                    case 1: k_cb<3><<<1024, 256, 0, stream>>>(xx, cb_ws, cb_bs, cbp, 1); break;
                    case 2: k_cb<9><<<1024, 256, 0, stream>>>(xx, cb_ws, cb_bs, cbp, 2); break;
                    case 3: k_cb<27><<<1024, 256, 0, stream>>>(xx, cb_ws, cb_bs, cbp, 3); break;
                }
            }
        }
    } else {
        // Fallback: R27-exact per-layer trio + k_lvcP without embed.
        for (int L = 0; L < 4; ++L) {
            switch (L) {
                case 0: k_trio<1><<<2113, 256, 0, stream>>>(xx, cb_ws, cb_bs, cbp,
                            ker_w, ker_b, Whip[0], Wlop[0], Bpkp[0], hp,
                            bias_w, bias_b, kbLp[0], L); break;
                case 1: k_trio<3><<<2113, 256, 0, stream>>>(xx, cb_ws, cb_bs, cbp,
                            ker_w, ker_b, Whip[0], Wlop[0], Bpkp[0], hp,
                            bias_w, bias_b, kbLp[0], L); break;
                case 2: k_trio<9><<<2113, 256, 0, stream>>>(xx, cb_ws, cb_bs, cbp,
                            ker_w, ker_b, Whip[0], Wlop[0], Bpkp[0], hp,
                            bias_w, bias_b, kbLp[0], L); break;
                case 3: k_trio<27><<<2113, 256, 0, stream>>>(xx, cb_ws, cb_bs, cbp,
                            ker_w, ker_b, Whip[0], Wlop[0], Bpkp[0], hp,
                            bias_w, bias_b, kbLp[0], L); break;
            }
            k_lvcP<<<1024, 256, 0, stream>>>(hp, cbp, kbLp[0],
                Whip[0], Wlop[0], Bpkp[0], xx,
                ker_w, ker_b, Whip[0], Wlop[0], Bpkp[0], kbLp[0],
                bias_w, bias_b, 0);
        }
    }
}

// Round 15
// 804.262 us; speedup vs baseline: 1.0546x; 1.0546x over previous
//
#include <hip/hip_runtime.h>
#include <math.h>

// LVCBlock forward, MI355X (gfx950).
// Shapes: B=16, CIN=32, CCOND=100, Lc=512, HOP=8, T=4096, HID=64, NL=4, K=3, COUT=64.
// ALL inputs and the output are float32.
//
// R29 vs R28 (848us — embed falsified: k_lvcP 140us, embedded blocks contend;
// best remains R21/R27 trio @ ~825us):
//  k_lvc CHUNK-PAIR version: each pass processes chunks (c, c+1):
//   - phase-1 fills kc[0] and kc[1] (2x8KB single-buffered; LDS 40960 ->
//     4 blocks/CU unchanged, grid 1024);
//   - phase-2 loads each xv = cbb[...] ONCE (identical across chunks) and
//     feeds BOTH chunks' FMA chains -> cbb reads halve (FETCH 33->~26MB);
//   - pass-rounds halve (24->12), 2 barriers/pass (24 total, same as R21)
//     but each fences 2x work; chunk-1 loads overlap chunk-0 MFMAs.
//  Every accumulator chain (MFMA per (c,MT); phase-2 ik-ascending per
//  (c,thread)) is order-identical to R21 -> bit-identical, absmax 0.03125.
//  Guard: VGPR must stay <=128 (4 waves/SIMD), WRITE 8MB.
//  Tail R27-EXACT (prologue, 6x k_res, per-layer trio).
// Workspace 19.51MB (R21 layout). absmax must stay 0.03125.

#define DEV __device__ __forceinline__

typedef unsigned short ushort;
typedef unsigned int uint;
typedef __attribute__((ext_vector_type(8))) short short8;   // 8 bf16 (4 VGPRs)
typedef __attribute__((ext_vector_type(4))) float f32x4;
typedef __attribute__((ext_vector_type(2))) float f32x2;

DEV float lrelu(float x) { return x > 0.f ? x : 0.2f * x; }

DEV ushort f2bf(float f) {                     // fp32 -> bf16 bits, RNE
    uint u = __float_as_uint(f);
    return (ushort)((u + 0x7fffu + ((u >> 16) & 1u)) >> 16);
}
DEV float bf2f(ushort b) { return __uint_as_float(((uint)b) << 16); }

// ---------------- kernel predictor input conv body (100->64, k=5, pad=2) + lrelu
DEV void pred_body(int idx, const float* __restrict__ c, const float* __restrict__ w,
                   const float* __restrict__ bias, float* __restrict__ hp) {
    int l4 = idx & 127, co = (idx >> 7) & 63, b = idx >> 13;
    int l0 = l4 << 2;
    float a0, a1, a2, a3;
    a0 = a1 = a2 = a3 = bias[co];
    for (int ci = 0; ci < 100; ++ci) {
        const float* crow = c + (b * 100 + ci) * 512;
        const float* wrow = w + (co * 100 + ci) * 5;
        float f0, f1, f2, f3, f4, f5, f6, f7;          // p = l0-2 .. l0+5
        if (l0 == 0) {
            float2 pb = *(const float2*)(crow + 0);
            float2 pc = *(const float2*)(crow + 2);
            float2 pd = *(const float2*)(crow + 4);
            f0 = 0.f; f1 = 0.f;
            f2 = pb.x; f3 = pb.y; f4 = pc.x; f5 = pc.y; f6 = pd.x; f7 = pd.y;
        } else if (l0 == 508) {
            float2 pa = *(const float2*)(crow + 506);
            float2 pb = *(const float2*)(crow + 508);
            float2 pc = *(const float2*)(crow + 510);
            f0 = pa.x; f1 = pa.y; f2 = pb.x; f3 = pb.y; f4 = pc.x; f5 = pc.y;
            f6 = 0.f; f7 = 0.f;
        } else {
            float2 pa = *(const float2*)(crow + l0 - 2);
            float2 pb = *(const float2*)(crow + l0);
            float2 pc = *(const float2*)(crow + l0 + 2);
            float2 pd = *(const float2*)(crow + l0 + 4);
            f0 = pa.x; f1 = pa.y; f2 = pb.x; f3 = pb.y; f4 = pc.x; f5 = pc.y;
            f6 = pd.x; f7 = pd.y;
        }
        float w0 = wrow[0], w1 = wrow[1], w2 = wrow[2], w3 = wrow[3], w4 = wrow[4];
        a0 += f0 * w0; a0 += f1 * w1; a0 += f2 * w2; a0 += f3 * w3; a0 += f4 * w4;
        a1 += f1 * w0; a1 += f2 * w1; a1 += f3 * w2; a1 += f4 * w3; a1 += f5 * w4;
        a2 += f2 * w0; a2 += f3 * w1; a2 += f4 * w2; a2 += f5 * w3; a2 += f6 * w4;
        a3 += f3 * w0; a3 += f4 * w1; a3 += f5 * w2; a3 += f6 * w3; a3 += f7 * w4;
    }
    float* hrow = hp + (size_t)(b * 64 + co) * 520 + 4 + l0;
    hrow[0] = lrelu(a0); hrow[1] = lrelu(a1); hrow[2] = lrelu(a2); hrow[3] = lrelu(a3);
    if (l0 == 0) hrow[-1] = 0.f;            // pad zeros (ws re-poisoned each call)
    if (l0 == 508) hrow[4] = 0.f;
}

// ---------------- convt_pre body: lrelu then ConvTranspose1d(32->32, k=16, s=8, p=4)
DEV void convt_body(int relblk, int s, const float* __restrict__ x,
                    const float* __restrict__ w, const float* __restrict__ bias,
                    float* __restrict__ xx) {
    int co = relblk & 31, b = relblk >> 5;
    float acc[8];
    float bz = bias[co];
#pragma unroll
    for (int m = 0; m < 8; ++m) acc[m] = bz;
    for (int ci = 0; ci < 32; ++ci) {
        const float* xr = x + (b * 32 + ci) * 512;
        float a = (s < 512) ? lrelu(xr[s]) : 0.f;      // FMA-with-0 == skip, exact
        float p = (s >= 1) ? lrelu(xr[s - 1]) : 0.f;
        const float* wr = w + (ci * 32 + co) * 16;
        float4 q0 = *(const float4*)(wr);
        float4 q1 = *(const float4*)(wr + 4);
        float4 q2 = *(const float4*)(wr + 8);
        float4 q3 = *(const float4*)(wr + 12);
        float wgt[16] = {q0.x, q0.y, q0.z, q0.w, q1.x, q1.y, q1.z, q1.w,
                         q2.x, q2.y, q2.z, q2.w, q3.x, q3.y, q3.z, q3.w};
#pragma unroll
        for (int m = 0; m < 8; ++m) {
            acc[m] += a * wgt[m];                      // s0 term first (orig order)
            acc[m] += p * wgt[m + 8];                  // then s0-1 term
        }
    }
    int t0 = 8 * s - 4;
    float* xrow = xx + (size_t)(b * 32 + co) * 4096;
    if (s >= 1 && s < 512) {
#pragma unroll
        for (int m = 0; m < 8; m += 2)
            *(float2*)(xrow + t0 + m) = make_float2(acc[m], acc[m + 1]);
    } else {
#pragma unroll
        for (int m = 0; m < 8; ++m) {
            int t = t0 + m;
            if (t >= 0 && t < 4096) xrow[t] = acc[m];
        }
    }
}

// ---------------- fused prologue: pred_in (blocks [0,228)) || convt ([228,740))
__global__ __launch_bounds__(576) void
k_fused_pc(const float* __restrict__ c, const float* __restrict__ in_w,
           const float* __restrict__ in_b, float* __restrict__ hp,
           const float* __restrict__ x, const float* __restrict__ ct_w,
           const float* __restrict__ ct_b, float* __restrict__ xx) {
    int blk = blockIdx.x;
    if (blk < 228) {
        int idx = blk * 576 + threadIdx.x;
        if (idx < 131072) pred_body(idx, c, in_w, in_b, hp);
    } else {
        int s = threadIdx.x;
        if (s <= 512) convt_body(blk - 228, s, x, ct_w, ct_b, xx);
    }
}

// ---------------- residual conv (64->64, k=3, pad=1) + lrelu, optional accumulate
__global__ void k_res(const float* __restrict__ src, const float* __restrict__ w,
                      const float* __restrict__ bias, float* __restrict__ dst,
                      const float* __restrict__ accum) {
    int idx = blockIdx.x * 256 + threadIdx.x;          // 16*64*128
    int l4 = idx & 127, co = (idx >> 7) & 63, b = idx >> 13;
    int l0 = l4 << 2;
    float a0, a1, a2, a3;
    a0 = a1 = a2 = a3 = bias[co];
    for (int ci = 0; ci < 64; ++ci) {
        const float* row = src + (size_t)(b * 64 + ci) * 520 + 4;
        float e0 = row[l0 - 1];
        float2 m01 = *(const float2*)(row + l0);
        float2 m23 = *(const float2*)(row + l0 + 2);
        float e1 = row[l0 + 4];
        const float* wr = w + (co * 64 + ci) * 3;
        float w0 = wr[0], w1 = wr[1], w2 = wr[2];
        a0 += e0 * w0;    a0 += m01.x * w1; a0 += m01.y * w2;
        a1 += m01.x * w0; a1 += m01.y * w1; a1 += m23.x * w2;
        a2 += m01.y * w0; a2 += m23.x * w1; a2 += m23.y * w2;
        a3 += m23.x * w0; a3 += m23.y * w1; a3 += e1 * w2;
    }
    float v0 = lrelu(a0), v1 = lrelu(a1), v2 = lrelu(a2), v3 = lrelu(a3);
    size_t rb = (size_t)(b * 64 + co) * 520 + 4 + l0;
    if (accum) {
        const float* ar = accum + rb;
        v0 += ar[0]; v1 += ar[1]; v2 += ar[2]; v3 += ar[3];
    }
    float* dr = dst + rb;
    dr[0] = v0; dr[1] = v1; dr[2] = v2; dr[3] = v3;
    if (l0 == 0) dr[-1] = 0.f;
    if (l0 == 508) dr[4] = 0.f;
}

// ---------------- bias head body, ONE layer's 64 channels (k=3, pad=1)
DEV void head_body(int idx, const float* __restrict__ hp, const float* __restrict__ w,
                   const float* __restrict__ bias, float* __restrict__ out, int layer) {
    int l4 = idx & 127, o = (idx >> 7) & 63, b = idx >> 13;
    int l0 = l4 << 2;
    int ch = layer * 64 + o;
    float a0, a1, a2, a3;
    a0 = a1 = a2 = a3 = bias[ch];
    for (int ci = 0; ci < 64; ++ci) {
        const float* row = hp + (size_t)(b * 64 + ci) * 520 + 4;
        float e0 = row[l0 - 1];
        float2 m01 = *(const float2*)(row + l0);
        float2 m23 = *(const float2*)(row + l0 + 2);
        float e1 = row[l0 + 4];
        const float* wr = w + (ch * 64 + ci) * 3;
        float w0 = wr[0], w1 = wr[1], w2 = wr[2];
        a0 += e0 * w0;    a0 += m01.x * w1; a0 += m01.y * w2;
        a1 += m01.x * w0; a1 += m01.y * w1; a1 += m23.x * w2;
        a2 += m01.y * w0; a2 += m23.x * w1; a2 += m23.y * w2;
        a3 += m23.x * w0; a3 += m23.y * w1; a3 += e1 * w2;
    }
    float* orow = out + (size_t)(b * 64 + o) * 512 + l0;
    orow[0] = a0; orow[1] = a1; orow[2] = a2; orow[3] = a3;
}

// ---------------- pack body (ONE layer), INVERSE mapping: idx=(ch, 8-col grp).
DEV void pack_dev(int relblk, int tid, const float* __restrict__ ker_w,
                  const float* __restrict__ ker_b, ushort* __restrict__ WhiB,
                  ushort* __restrict__ WloB, float* __restrict__ BpkB, int layer) {
    if (relblk == 576) {                // bias pack: 6144 entries
        for (int idx = tid; idx < 6144; idx += 256) {
            int c = idx / 384, r = idx - c * 384;
            int ik = r >> 2, oc = r & 3;
            int i = ik / 3, kk = ik - i * 3;
            int o = 32 * (oc & 1) + 2 * c + (oc >> 1);
            BpkB[idx] = ker_b[layer * 6144 + (i * 64 + o) * 3 + kk];
        }
        return;
    }
    int idx = relblk * 256 + tid;                      // < 147456 = 6144 ch * 24 cg
    int cg = idx % 24, ch = idx / 24;
    int q3 = ch / 3, kk = ch - q3 * 3;                 // ch = (i*64+o)*3 + kk
    int o = q3 & 63, i = q3 >> 6;
    int oc = ((o & 1) << 1) | (o >> 5);                // o = 32*(oc&1) + 2c + (oc>>1)
    int c = (o & 31) >> 1;
    int r = (i * 3 + kk) * 4 + oc;                     // r = ik*4 + oc
    int mt = r >> 4, m = r & 15;
    int ks = cg >> 2, quad = cg & 3;                   // col = ks*32 + quad*8 + j
    const float* src = ker_w + ((size_t)(layer * 6144 + ch)) * 192 + cg * 8;
    float4 fa = *(const float4*)(src);
    float4 fb = *(const float4*)(src + 4);
    float f[8] = {fa.x, fa.y, fa.z, fa.w, fb.x, fb.y, fb.z, fb.w};
    uint uh[4], ul[4];
#pragma unroll
    for (int t = 0; t < 4; ++t) {
        float f0 = f[2 * t], f1 = f[2 * t + 1];
        ushort h0 = f2bf(f0), h1 = f2bf(f1);
        ushort l0 = f2bf(f0 - bf2f(h0)), l1 = f2bf(f1 - bf2f(h1));
        uh[t] = (uint)h0 | ((uint)h1 << 16);
        ul[t] = (uint)l0 | ((uint)l1 << 16);
    }
    size_t base = ((size_t)((c * 24 + mt) * 6 + ks) * 64 + quad * 16 + m) * 8;
    *reinterpret_cast<uint4*>(WhiB + base) = make_uint4(uh[0], uh[1], uh[2], uh[3]);
    *reinterpret_cast<uint4*>(WloB + base) = make_uint4(ul[0], ul[1], ul[2], ul[3]);
}

// ---------------- dilated conv block body, LDS-staged -> PADDED cb (stride 4104)
template <int D>
DEV void cblock2_body(int blk, int tid, const float* __restrict__ xx,
                      const float* __restrict__ w, const float* __restrict__ bias,
                      float* __restrict__ cbp, int layer,
                      float (*lx)[132], float (*wl)[100]) {
    int tt = blk & 63, b = blk >> 6;                   // 1024 rel blocks
    int W0 = tt * 64 - 28;

    {
        int r = tid >> 3, cg = (tid & 7) * 16;
        const float* srow = xx + (size_t)(b * 32 + r) * 4096 + W0 + cg;
        float* drow = &lx[r][cg];
        if (tt > 0 && tt < 63) {                       // fully interior: vector
#pragma unroll
            for (int q = 0; q < 4; ++q) {
                float4 v = *(const float4*)(srow + q * 4);
                drow[q * 4 + 0] = lrelu(v.x); drow[q * 4 + 1] = lrelu(v.y);
                drow[q * 4 + 2] = lrelu(v.z); drow[q * 4 + 3] = lrelu(v.w);
            }
        } else {                                       // edge tiles: guarded
#pragma unroll
            for (int j = 0; j < 16; ++j) {
                int p = W0 + cg + j;
                drow[j] = (p >= 0 && p < 4096) ? lrelu(srow[j]) : 0.f;
            }
        }
    }
    for (int f = tid; f < 3072; f += 256)
        wl[f / 96][f % 96] = w[layer * 3072 + f];
    __syncthreads();

    int ci = tid >> 3, ug = tid & 7;
    int t0 = tt * 64 + ug * 8;
    int lb = ug * 8 + 28;
    float acc[8];
    float bz = bias[layer * 32 + ci];
#pragma unroll
    for (int u = 0; u < 8; ++u) acc[u] = bz;
    const float* Wr = &wl[ci][0];
    const float* Lb = &lx[0][lb];
    for (int c2 = 0; c2 < 32; ++c2) {
        float w0 = Wr[c2 * 3], w1 = Wr[c2 * 3 + 1], w2 = Wr[c2 * 3 + 2];
        const float* Lr = Lb + c2 * 132;
#pragma unroll
        for (int u = 0; u < 8; ++u) {
            float v0 = Lr[u - D], v1 = Lr[u], v2 = Lr[u + D];
            acc[u] += v0 * w0; acc[u] += v1 * w1; acc[u] += v2 * w2;
        }
    }
    float* crow = cbp + (size_t)(b * 32 + ci) * 4104 + 4 + t0;
#pragma unroll
    for (int u = 0; u < 8; u += 2)
        *(float2*)(crow + u) = make_float2(lrelu(acc[u]), lrelu(acc[u + 1]));
    if (t0 == 0) crow[-1] = 0.f;        // guard cells for k_lvc phase-2
    if (t0 == 4088) crow[8] = 0.f;      // data[4096]
}

// ---------------- per-layer trio (R21-exact): cblock2 [0,1024) || pack
// [1024,1601) || head [1601,2113).
template <int D>
__global__ __launch_bounds__(256) void
k_trio(const float* __restrict__ xx, const float* __restrict__ cb_ws,
       const float* __restrict__ cb_bs, float* __restrict__ cbp,
       const float* __restrict__ ker_w, const float* __restrict__ ker_b,
       ushort* __restrict__ Whi, ushort* __restrict__ Wlo, float* __restrict__ Bpk,
       const float* __restrict__ hp, const float* __restrict__ bias_w,
       const float* __restrict__ bias_b, float* __restrict__ kbL, int layer) {
    __shared__ float lx[32][132];
    __shared__ float wl[32][100];
    int blk = blockIdx.x;
    if (blk < 1024) {
        cblock2_body<D>(blk, threadIdx.x, xx, cb_ws, cb_bs, cbp, layer, lx, wl);
    } else if (blk < 1601) {
        pack_dev(blk - 1024, threadIdx.x, ker_w, ker_b, Whi, Wlo, Bpk, layer);
    } else {
        head_body((blk - 1601) * 256 + threadIdx.x, hp, bias_w, bias_b, kbL, layer);
    }
}

// ---------------- fused: split-precision MFMA kernel-head GEMM + einsum + gate
// R29 CHUNK-PAIR: pass processes chunks (c0, c0+1); kc[2][2048] single-buffered
// (LDS 40960 = R21, 4 blocks/CU); phase-2 loads xv once for both chunks.
// Every per-(c,MT) MFMA chain and per-(c,thread) ik-ascending FMA chain is
// order-identical to R21 -> bit-identical math.
__global__ __launch_bounds__(256) void
k_lvc(const float* __restrict__ h, const float* __restrict__ cbp,
      const float* __restrict__ kbL, const ushort* __restrict__ Whi,
      const ushort* __restrict__ Wlo, const float* __restrict__ Bpk,
      float* __restrict__ xx) {
    __shared__ ushort HfH[6144];        // 12288 B: ((nt*6+ks)*64+lane)*8+j
    __shared__ ushort HfL[6144];        // 12288 B
    __shared__ float kc[2 * 2048];      // 16384 B: kc[u][...] for chunk pair
    // total 40960 B -> 4 blocks/CU

    int tid = threadIdx.x;
    // bijective remap: XCD = blockIdx%8 shared by the 4 qtr of group g.
    int g = (blockIdx.x >> 5) * 8 + (blockIdx.x & 7);   // (b,lt) group in [0,256)
    int qtr = (blockIdx.x >> 3) & 3;
    int lt = g & 15;
    int b = g >> 4;
    int l0 = lt * 32;

    // ---- build h hi/lo B-fragments ONCE into LDS (flat fragment order).
    for (int v = tid; v < 6144; v += 256) {
        int j = v & 7;
        int lane_ = (v >> 3) & 63;
        int r2 = v >> 9;                // nt_*6 + ks
        int ks = r2 % 6, nt_ = r2 / 6;
        int n = nt_ * 16 + (lane_ & 15);
        int cj = ks * 32 + (lane_ >> 4) * 8 + j;
        int ci = cj / 3, jt = cj - ci * 3;
        int p = l0 + n + jt - 1;
        float val = h[(size_t)(b * 64 + ci) * 520 + 4 + p];   // padded, p in [-1,512]
        ushort hi = f2bf(val);
        HfH[v] = hi;
        HfL[v] = f2bf(val - bf2f(hi));
    }
    __syncthreads();

    int wave = tid >> 6, lane = tid & 63;
    int n16 = lane & 15, quad = lane >> 4;
    int nt = wave & 1;                  // this wave's n-tile
    int mt0 = (wave >> 1) * 2;          // this wave's 2 local m-tiles

    const ushort* hfh = &HfH[(nt * 6) * 512 + lane * 8];
    const ushort* hfl = &HfL[(nt * 6) * 512 + lane * 8];

    int h8 = tid & 7, n2 = tid >> 3;    // phase-2: hop h8, location n2 in [0,32)
    int lg = l0 + n2;
    int tglob = lg * 8 + h8;
    const float* cbb = cbp + (size_t)b * 32 * 4104;
    const float* kbb = kbL + b * 64 * 512;
    float* xxb = xx + b * 32 * 4096;

    for (int hh = 0; hh < 2; ++hh) {
        int c0 = qtr * 4 + 2 * hh;      // chunk pair (c0, c0+1)
        f32x2 A01_0 = {0.f, 0.f}, A23_0 = {0.f, 0.f};
        f32x2 A01_1 = {0.f, 0.f}, A23_1 = {0.f, 0.f};
        for (int p = 0; p < 6; ++p) {
            // ---- phase 1: both chunks' MT jobs (independent chains; loads of
            // u=1 overlap MFMAs of u=0). Per-chunk body identical to R21.
#pragma unroll
            for (int u = 0; u < 2; ++u) {
                int c = c0 + u;
                int MT0 = p * 4 + mt0;
                const ushort* wh0 = Whi + (((size_t)(c * 24 + MT0) * 6) * 64 + lane) * 8;
                const ushort* wl0 = Wlo + (((size_t)(c * 24 + MT0) * 6) * 64 + lane) * 8;
                f32x4 acc0 = {0.f, 0.f, 0.f, 0.f};
                f32x4 acc1 = {0.f, 0.f, 0.f, 0.f};
                __builtin_amdgcn_s_setprio(1);
#pragma unroll 2
                for (int ks = 0; ks < 6; ++ks) {
                    short8 bhf = *reinterpret_cast<const short8*>(hfh + ks * 512);
                    short8 blf = *reinterpret_cast<const short8*>(hfl + ks * 512);
                    short8 w0h = *reinterpret_cast<const short8*>(wh0 + ks * 512);
                    short8 w0l = *reinterpret_cast<const short8*>(wl0 + ks * 512);
                    acc0 = __builtin_amdgcn_mfma_f32_16x16x32_bf16(w0h, bhf, acc0, 0, 0, 0);
                    acc0 = __builtin_amdgcn_mfma_f32_16x16x32_bf16(w0l, bhf, acc0, 0, 0, 0);
                    acc0 = __builtin_amdgcn_mfma_f32_16x16x32_bf16(w0h, blf, acc0, 0, 0, 0);
                    short8 w1h = *reinterpret_cast<const short8*>(wh0 + 3072 + ks * 512);
                    short8 w1l = *reinterpret_cast<const short8*>(wl0 + 3072 + ks * 512);
                    acc1 = __builtin_amdgcn_mfma_f32_16x16x32_bf16(w1h, bhf, acc1, 0, 0, 0);
                    acc1 = __builtin_amdgcn_mfma_f32_16x16x32_bf16(w1l, bhf, acc1, 0, 0, 0);
                    acc1 = __builtin_amdgcn_mfma_f32_16x16x32_bf16(w1h, blf, acc1, 0, 0, 0);
                }
                __builtin_amdgcn_s_setprio(0);
                acc0 += *reinterpret_cast<const f32x4*>(Bpk + c * 384 + MT0 * 16 + quad * 4);
                acc1 += *reinterpret_cast<const f32x4*>(Bpk + c * 384 + (MT0 + 1) * 16 + quad * 4);
                // D: col=lane&15 -> n16, row=quad*4+reg; ik_local = lmt*4+quad, oc=reg
                *reinterpret_cast<f32x4*>(
                    &kc[u * 2048 + ((mt0 * 4 + quad) * 32 + nt * 16 + n16) * 4]) = acc0;
                *reinterpret_cast<f32x4*>(
                    &kc[u * 2048 + (((mt0 + 1) * 4 + quad) * 32 + nt * 16 + n16) * 4]) = acc1;
            }
            __syncthreads();            // kc(p) complete for both chunks

            // ---- phase 2 partial: xv loaded ONCE, feeds both chunks' chains.
#pragma unroll
            for (int ikk = 0; ikk < 16; ++ikk) {
                int ik = p * 16 + ikk;
                int i = ik / 3, kk = ik - i * 3;
                float xv = cbb[(size_t)i * 4104 + 3 + tglob + kk];
                f32x2 xv2 = {xv, xv};
                float4 kv0 = *reinterpret_cast<const float4*>(&kc[(ikk * 32 + n2) * 4]);
                float4 kv1 = *reinterpret_cast<const float4*>(&kc[2048 + (ikk * 32 + n2) * 4]);
                f32x2 klo0 = {kv0.x, kv0.y}, khi0 = {kv0.z, kv0.w};
                f32x2 klo1 = {kv1.x, kv1.y}, khi1 = {kv1.z, kv1.w};
                A01_0 = __builtin_elementwise_fma(klo0, xv2, A01_0);
                A23_0 = __builtin_elementwise_fma(khi0, xv2, A23_0);
                A01_1 = __builtin_elementwise_fma(klo1, xv2, A01_1);
                A23_1 = __builtin_elementwise_fma(khi1, xv2, A23_1);
            }
            __syncthreads();            // kc consumed; next phase-1 may overwrite
        }
        // ---- gate both chunks: oc {0,1,2,3} -> o {2c, 32+2c, 2c+1, 32+2c+1}
        {
            int c = c0;
            float pa = A01_0.x + kbb[(2 * c) * 512 + lg];
            float pb = A01_0.y + kbb[(32 + 2 * c) * 512 + lg];
            float g2 = (1.f / (1.f + expf(-pa))) * tanhf(pb);
            xxb[(2 * c) * 4096 + tglob] += g2;
            pa = A23_0.x + kbb[(2 * c + 1) * 512 + lg];
            pb = A23_0.y + kbb[(32 + 2 * c + 1) * 512 + lg];
            g2 = (1.f / (1.f + expf(-pa))) * tanhf(pb);
            xxb[(2 * c + 1) * 4096 + tglob] += g2;
            c = c0 + 1;
            pa = A01_1.x + kbb[(2 * c) * 512 + lg];
            pb = A01_1.y + kbb[(32 + 2 * c) * 512 + lg];
            g2 = (1.f / (1.f + expf(-pa))) * tanhf(pb);
            xxb[(2 * c) * 4096 + tglob] += g2;
            pa = A23_1.x + kbb[(2 * c + 1) * 512 + lg];
            pb = A23_1.y + kbb[(32 + 2 * c + 1) * 512 + lg];
            g2 = (1.f / (1.f + expf(-pa))) * tanhf(pb);
            xxb[(2 * c + 1) * 4096 + tglob] += g2;
        }
    }
}

extern "C" void kernel_launch(void* const* d_in, const int* in_sizes, int n_in,
                              void* d_out, int out_size, void* d_ws, size_t ws_size,
                              hipStream_t stream) {
    const float* x      = (const float*)d_in[0];
    const float* c      = (const float*)d_in[1];
    const float* in_w   = (const float*)d_in[2];
    const float* in_b   = (const float*)d_in[3];
    const float* res_ws = (const float*)d_in[4];
    const float* res_bs = (const float*)d_in[5];
    const float* ker_w  = (const float*)d_in[6];
    const float* ker_b  = (const float*)d_in[7];
    const float* bias_w = (const float*)d_in[8];
    const float* bias_b = (const float*)d_in[9];
    const float* ct_w   = (const float*)d_in[10];
    const float* ct_b   = (const float*)d_in[11];
    const float* cb_ws  = (const float*)d_in[12];
    const float* cb_bs  = (const float*)d_in[13];

    float* ws   = (float*)d_ws;
    float* hp   = ws;                         // [0, 532480)       16*64*520 padded
    float* kbL  = ws + 532480;                // [532480, 1056768) 16*64*512
    float* tmp  = ws + 1056768;               // [1056768, 1589248) padded
    float* cbp  = ws + 1589248;               // [1589248, 3690496) 16*32*4104 padded
    ushort* Whi = (ushort*)(ws + 3690496);    // [3690496, 4280320)
    ushort* Wlo = (ushort*)(ws + 4280320);    // [4280320, 4870144)
    float* Bpk  = ws + 4870144;               // [4870144, 4876288)
    // high-water 19.51 MB (< 20.97 MB proven by R2's pass)
    float* xx   = (float*)d_out;              // state tensor lives in d_out

    k_fused_pc<<<740, 576, 0, stream>>>(c, in_w, in_b, hp, x, ct_w, ct_b, xx);
    for (int j = 0; j < 3; ++j) {
        k_res<<<512, 256, 0, stream>>>(hp,  res_ws + (j * 2 + 0) * 64 * 64 * 3,
                                       res_bs + (j * 2 + 0) * 64, tmp, nullptr);
        k_res<<<512, 256, 0, stream>>>(tmp, res_ws + (j * 2 + 1) * 64 * 64 * 3,
                                       res_bs + (j * 2 + 1) * 64, hp, hp);
    }

    for (int L = 0; L < 4; ++L) {
        switch (L) {
            case 0: k_trio<1><<<2113, 256, 0, stream>>>(xx, cb_ws, cb_bs, cbp,
                        ker_w, ker_b, Whi, Wlo, Bpk, hp, bias_w, bias_b, kbL, L); break;
            case 1: k_trio<3><<<2113, 256, 0, stream>>>(xx, cb_ws, cb_bs, cbp,
                        ker_w, ker_b, Whi, Wlo, Bpk, hp, bias_w, bias_b, kbL, L); break;
            case 2: k_trio<9><<<2113, 256, 0, stream>>>(xx, cb_ws, cb_bs, cbp,
                        ker_w, ker_b, Whi, Wlo, Bpk, hp, bias_w, bias_b, kbL, L); break;
            case 3: k_trio<27><<<2113, 256, 0, stream>>>(xx, cb_ws, cb_bs, cbp,
                        ker_w, ker_b, Whi, Wlo, Bpk, hp, bias_w, bias_b, kbL, L); break;
        }
        k_lvc<<<1024, 256, 0, stream>>>(hp, cbp, kbL, Whi, Wlo, Bpk, xx);
    }
}

// Round 16
// 771.113 us; speedup vs baseline: 1.0999x; 1.0430x over previous
//
#include <hip/hip_runtime.h>
#include <math.h>

// LVCBlock forward, MI355X (gfx950).
// Shapes: B=16, CIN=32, CCOND=100, Lc=512, HOP=8, T=4096, HID=64, NL=4, K=3, COUT=64.
// ALL inputs and the output are float32.
//
// R30 vs R29 (804.3us WIN — chunk-pair k_lvc 114us; tail 348us):
//  k_res and head re-tiled with the cblock2 recipe (R18's proven 5x pattern):
//  block = (b, 32-l tile); stage hp halo window 64x34 floats (8.7KB LDS) ONCE;
//  thread = (co, l-quad) computes 8 outputs from LDS. Global loads drop ~45x.
//  FMA chains EXACT (per output: bias, ci ascending, taps w0/w1/w2; lrelu
//  before accum-add) -> bit-identical. head keeps same tiling inside trio
//  (blocks [1601,1857), reuses lx LDS storage, branch-exclusive).
//  k_lvc R29-EXACT (chunk-pair, 114us proven). absmax must stay 0.03125.
// Workspace 19.51MB (R21 layout).

#define DEV __device__ __forceinline__

typedef unsigned short ushort;
typedef unsigned int uint;
typedef __attribute__((ext_vector_type(8))) short short8;   // 8 bf16 (4 VGPRs)
typedef __attribute__((ext_vector_type(4))) float f32x4;
typedef __attribute__((ext_vector_type(2))) float f32x2;

DEV float lrelu(float x) { return x > 0.f ? x : 0.2f * x; }

DEV ushort f2bf(float f) {                     // fp32 -> bf16 bits, RNE
    uint u = __float_as_uint(f);
    return (ushort)((u + 0x7fffu + ((u >> 16) & 1u)) >> 16);
}
DEV float bf2f(ushort b) { return __uint_as_float(((uint)b) << 16); }

// ---------------- kernel predictor input conv body (100->64, k=5, pad=2) + lrelu
DEV void pred_body(int idx, const float* __restrict__ c, const float* __restrict__ w,
                   const float* __restrict__ bias, float* __restrict__ hp) {
    int l4 = idx & 127, co = (idx >> 7) & 63, b = idx >> 13;
    int l0 = l4 << 2;
    float a0, a1, a2, a3;
    a0 = a1 = a2 = a3 = bias[co];
    for (int ci = 0; ci < 100; ++ci) {
        const float* crow = c + (b * 100 + ci) * 512;
        const float* wrow = w + (co * 100 + ci) * 5;
        float f0, f1, f2, f3, f4, f5, f6, f7;          // p = l0-2 .. l0+5
        if (l0 == 0) {
            float2 pb = *(const float2*)(crow + 0);
            float2 pc = *(const float2*)(crow + 2);
            float2 pd = *(const float2*)(crow + 4);
            f0 = 0.f; f1 = 0.f;
            f2 = pb.x; f3 = pb.y; f4 = pc.x; f5 = pc.y; f6 = pd.x; f7 = pd.y;
        } else if (l0 == 508) {
            float2 pa = *(const float2*)(crow + 506);
            float2 pb = *(const float2*)(crow + 508);
            float2 pc = *(const float2*)(crow + 510);
            f0 = pa.x; f1 = pa.y; f2 = pb.x; f3 = pb.y; f4 = pc.x; f5 = pc.y;
            f6 = 0.f; f7 = 0.f;
        } else {
            float2 pa = *(const float2*)(crow + l0 - 2);
            float2 pb = *(const float2*)(crow + l0);
            float2 pc = *(const float2*)(crow + l0 + 2);
            float2 pd = *(const float2*)(crow + l0 + 4);
            f0 = pa.x; f1 = pa.y; f2 = pb.x; f3 = pb.y; f4 = pc.x; f5 = pc.y;
            f6 = pd.x; f7 = pd.y;
        }
        float w0 = wrow[0], w1 = wrow[1], w2 = wrow[2], w3 = wrow[3], w4 = wrow[4];
        a0 += f0 * w0; a0 += f1 * w1; a0 += f2 * w2; a0 += f3 * w3; a0 += f4 * w4;
        a1 += f1 * w0; a1 += f2 * w1; a1 += f3 * w2; a1 += f4 * w3; a1 += f5 * w4;
        a2 += f2 * w0; a2 += f3 * w1; a2 += f4 * w2; a2 += f5 * w3; a2 += f6 * w4;
        a3 += f3 * w0; a3 += f4 * w1; a3 += f5 * w2; a3 += f6 * w3; a3 += f7 * w4;
    }
    float* hrow = hp + (size_t)(b * 64 + co) * 520 + 4 + l0;
    hrow[0] = lrelu(a0); hrow[1] = lrelu(a1); hrow[2] = lrelu(a2); hrow[3] = lrelu(a3);
    if (l0 == 0) hrow[-1] = 0.f;            // pad zeros (ws re-poisoned each call)
    if (l0 == 508) hrow[4] = 0.f;
}

// ---------------- convt_pre body: lrelu then ConvTranspose1d(32->32, k=16, s=8, p=4)
DEV void convt_body(int relblk, int s, const float* __restrict__ x,
                    const float* __restrict__ w, const float* __restrict__ bias,
                    float* __restrict__ xx) {
    int co = relblk & 31, b = relblk >> 5;
    float acc[8];
    float bz = bias[co];
#pragma unroll
    for (int m = 0; m < 8; ++m) acc[m] = bz;
    for (int ci = 0; ci < 32; ++ci) {
        const float* xr = x + (b * 32 + ci) * 512;
        float a = (s < 512) ? lrelu(xr[s]) : 0.f;      // FMA-with-0 == skip, exact
        float p = (s >= 1) ? lrelu(xr[s - 1]) : 0.f;
        const float* wr = w + (ci * 32 + co) * 16;
        float4 q0 = *(const float4*)(wr);
        float4 q1 = *(const float4*)(wr + 4);
        float4 q2 = *(const float4*)(wr + 8);
        float4 q3 = *(const float4*)(wr + 12);
        float wgt[16] = {q0.x, q0.y, q0.z, q0.w, q1.x, q1.y, q1.z, q1.w,
                         q2.x, q2.y, q2.z, q2.w, q3.x, q3.y, q3.z, q3.w};
#pragma unroll
        for (int m = 0; m < 8; ++m) {
            acc[m] += a * wgt[m];                      // s0 term first (orig order)
            acc[m] += p * wgt[m + 8];                  // then s0-1 term
        }
    }
    int t0 = 8 * s - 4;
    float* xrow = xx + (size_t)(b * 32 + co) * 4096;
    if (s >= 1 && s < 512) {
#pragma unroll
        for (int m = 0; m < 8; m += 2)
            *(float2*)(xrow + t0 + m) = make_float2(acc[m], acc[m + 1]);
    } else {
#pragma unroll
        for (int m = 0; m < 8; ++m) {
            int t = t0 + m;
            if (t >= 0 && t < 4096) xrow[t] = acc[m];
        }
    }
}

// ---------------- fused prologue: pred_in (blocks [0,228)) || convt ([228,740))
__global__ __launch_bounds__(576) void
k_fused_pc(const float* __restrict__ c, const float* __restrict__ in_w,
           const float* __restrict__ in_b, float* __restrict__ hp,
           const float* __restrict__ x, const float* __restrict__ ct_w,
           const float* __restrict__ ct_b, float* __restrict__ xx) {
    int blk = blockIdx.x;
    if (blk < 228) {
        int idx = blk * 576 + threadIdx.x;
        if (idx < 131072) pred_body(idx, c, in_w, in_b, hp);
    } else {
        int s = threadIdx.x;
        if (s <= 512) convt_body(blk - 228, s, x, ct_w, ct_b, xx);
    }
}

// ---------------- residual conv, LDS-staged (64->64, k=3, pad=1) + lrelu (+accum)
// block = (b, lt): stages hp[64][lt*32-1 .. lt*32+32] (64x34) once; thread =
// (co = tid&63, lq = tid>>6) computes 8 outputs. FMA order per output EXACT:
// bias; ci ascending; taps w0,w1,w2. lrelu THEN accum-add (orig order).
__global__ __launch_bounds__(256) void
k_res2(const float* __restrict__ src, const float* __restrict__ w,
       const float* __restrict__ bias, float* __restrict__ dst,
       const float* __restrict__ accum) {
    __shared__ float ls[64][34];        // 8704 B
    int lt = blockIdx.x & 15, b = blockIdx.x >> 4;     // grid 256
    int tid = threadIdx.x;
    // stage: 2176 floats; src rows are PADDED (stride 520, base +4) so
    // positions lt*32-1 .. lt*32+32 are always in-bounds (pads are zeros).
    for (int f = tid; f < 2176; f += 256) {
        int ci = f / 34, pos = f - ci * 34;
        ls[ci][pos] = src[(size_t)(b * 64 + ci) * 520 + 4 + lt * 32 - 1 + pos];
    }
    __syncthreads();

    int co = tid & 63, lq = tid >> 6;   // 8 outputs at l = lt*32 + lq*8 + j
    float acc[8];
    float bz = bias[co];
#pragma unroll
    for (int j = 0; j < 8; ++j) acc[j] = bz;
    for (int ci = 0; ci < 64; ++ci) {
        const float* wr = w + (co * 64 + ci) * 3;
        float w0 = wr[0], w1 = wr[1], w2 = wr[2];
        const float* base = &ls[ci][1 + lq * 8];
#pragma unroll
        for (int j = 0; j < 8; ++j) {
            acc[j] += base[j - 1] * w0;
            acc[j] += base[j]     * w1;
            acc[j] += base[j + 1] * w2;
        }
    }
    int l0 = lt * 32 + lq * 8;
    size_t rb = (size_t)(b * 64 + co) * 520 + 4 + l0;
    float v[8];
#pragma unroll
    for (int j = 0; j < 8; ++j) v[j] = lrelu(acc[j]);
    if (accum) {
        const float* ar = accum + rb;
#pragma unroll
        for (int j = 0; j < 8; ++j) v[j] += ar[j];
    }
    float* dr = dst + rb;
#pragma unroll
    for (int j = 0; j < 8; j += 4)
        *(float4*)(dr + j) = make_float4(v[j], v[j + 1], v[j + 2], v[j + 3]);
    if (lt == 0 && lq == 0) dr[-1] = 0.f;              // left pad for this row
    if (lt == 15 && lq == 3) dr[8] = 0.f;              // right pad (index 512)
}

// ---------------- bias head body (LDS-staged, ONE layer): block-relative.
// Same tiling as k_res2; writes kbL UNPADDED (stride 512). ls = 64x34 floats.
DEV void head2_body(int relb, int tid, const float* __restrict__ hp,
                    const float* __restrict__ w, const float* __restrict__ bias,
                    float* __restrict__ out, int layer, float* ls) {
    int lt = relb & 15, b = relb >> 4;                 // 256 rel blocks
    for (int f = tid; f < 2176; f += 256) {
        int ci = f / 34, pos = f - ci * 34;
        ls[ci * 34 + pos] = hp[(size_t)(b * 64 + ci) * 520 + 4 + lt * 32 - 1 + pos];
    }
    __syncthreads();

    int o = tid & 63, lq = tid >> 6;
    int ch = layer * 64 + o;
    float acc[8];
    float bz = bias[ch];
#pragma unroll
    for (int j = 0; j < 8; ++j) acc[j] = bz;
    for (int ci = 0; ci < 64; ++ci) {
        const float* wr = w + (ch * 64 + ci) * 3;
        float w0 = wr[0], w1 = wr[1], w2 = wr[2];
        const float* base = ls + ci * 34 + 1 + lq * 8;
#pragma unroll
        for (int j = 0; j < 8; ++j) {
            acc[j] += base[j - 1] * w0;
            acc[j] += base[j]     * w1;
            acc[j] += base[j + 1] * w2;
        }
    }
    int l0 = lt * 32 + lq * 8;
    float* orow = out + (size_t)(b * 64 + o) * 512 + l0;
#pragma unroll
    for (int j = 0; j < 8; j += 4)
        *(float4*)(orow + j) = make_float4(acc[j], acc[j + 1], acc[j + 2], acc[j + 3]);
}

// ---------------- pack body (ONE layer), INVERSE mapping: idx=(ch, 8-col grp).
DEV void pack_dev(int relblk, int tid, const float* __restrict__ ker_w,
                  const float* __restrict__ ker_b, ushort* __restrict__ WhiB,
                  ushort* __restrict__ WloB, float* __restrict__ BpkB, int layer) {
    if (relblk == 576) {                // bias pack: 6144 entries
        for (int idx = tid; idx < 6144; idx += 256) {
            int c = idx / 384, r = idx - c * 384;
            int ik = r >> 2, oc = r & 3;
            int i = ik / 3, kk = ik - i * 3;
            int o = 32 * (oc & 1) + 2 * c + (oc >> 1);
            BpkB[idx] = ker_b[layer * 6144 + (i * 64 + o) * 3 + kk];
        }
        return;
    }
    int idx = relblk * 256 + tid;                      // < 147456 = 6144 ch * 24 cg
    int cg = idx % 24, ch = idx / 24;
    int q3 = ch / 3, kk = ch - q3 * 3;                 // ch = (i*64+o)*3 + kk
    int o = q3 & 63, i = q3 >> 6;
    int oc = ((o & 1) << 1) | (o >> 5);                // o = 32*(oc&1) + 2c + (oc>>1)
    int c = (o & 31) >> 1;
    int r = (i * 3 + kk) * 4 + oc;                     // r = ik*4 + oc
    int mt = r >> 4, m = r & 15;
    int ks = cg >> 2, quad = cg & 3;                   // col = ks*32 + quad*8 + j
    const float* src = ker_w + ((size_t)(layer * 6144 + ch)) * 192 + cg * 8;
    float4 fa = *(const float4*)(src);
    float4 fb = *(const float4*)(src + 4);
    float f[8] = {fa.x, fa.y, fa.z, fa.w, fb.x, fb.y, fb.z, fb.w};
    uint uh[4], ul[4];
#pragma unroll
    for (int t = 0; t < 4; ++t) {
        float f0 = f[2 * t], f1 = f[2 * t + 1];
        ushort h0 = f2bf(f0), h1 = f2bf(f1);
        ushort l0 = f2bf(f0 - bf2f(h0)), l1 = f2bf(f1 - bf2f(h1));
        uh[t] = (uint)h0 | ((uint)h1 << 16);
        ul[t] = (uint)l0 | ((uint)l1 << 16);
    }
    size_t base = ((size_t)((c * 24 + mt) * 6 + ks) * 64 + quad * 16 + m) * 8;
    *reinterpret_cast<uint4*>(WhiB + base) = make_uint4(uh[0], uh[1], uh[2], uh[3]);
    *reinterpret_cast<uint4*>(WloB + base) = make_uint4(ul[0], ul[1], ul[2], ul[3]);
}

// ---------------- dilated conv block body, LDS-staged -> PADDED cb (stride 4104)
template <int D>
DEV void cblock2_body(int blk, int tid, const float* __restrict__ xx,
                      const float* __restrict__ w, const float* __restrict__ bias,
                      float* __restrict__ cbp, int layer,
                      float (*lx)[132], float (*wl)[100]) {
    int tt = blk & 63, b = blk >> 6;                   // 1024 rel blocks
    int W0 = tt * 64 - 28;

    {
        int r = tid >> 3, cg = (tid & 7) * 16;
        const float* srow = xx + (size_t)(b * 32 + r) * 4096 + W0 + cg;
        float* drow = &lx[r][cg];
        if (tt > 0 && tt < 63) {                       // fully interior: vector
#pragma unroll
            for (int q = 0; q < 4; ++q) {
                float4 v = *(const float4*)(srow + q * 4);
                drow[q * 4 + 0] = lrelu(v.x); drow[q * 4 + 1] = lrelu(v.y);
                drow[q * 4 + 2] = lrelu(v.z); drow[q * 4 + 3] = lrelu(v.w);
            }
        } else {                                       // edge tiles: guarded
#pragma unroll
            for (int j = 0; j < 16; ++j) {
                int p = W0 + cg + j;
                drow[j] = (p >= 0 && p < 4096) ? lrelu(srow[j]) : 0.f;
            }
        }
    }
    for (int f = tid; f < 3072; f += 256)
        wl[f / 96][f % 96] = w[layer * 3072 + f];
    __syncthreads();

    int ci = tid >> 3, ug = tid & 7;
    int t0 = tt * 64 + ug * 8;
    int lb = ug * 8 + 28;
    float acc[8];
    float bz = bias[layer * 32 + ci];
#pragma unroll
    for (int u = 0; u < 8; ++u) acc[u] = bz;
    const float* Wr = &wl[ci][0];
    const float* Lb = &lx[0][lb];
    for (int c2 = 0; c2 < 32; ++c2) {
        float w0 = Wr[c2 * 3], w1 = Wr[c2 * 3 + 1], w2 = Wr[c2 * 3 + 2];
        const float* Lr = Lb + c2 * 132;
#pragma unroll
        for (int u = 0; u < 8; ++u) {
            float v0 = Lr[u - D], v1 = Lr[u], v2 = Lr[u + D];
            acc[u] += v0 * w0; acc[u] += v1 * w1; acc[u] += v2 * w2;
        }
    }
    float* crow = cbp + (size_t)(b * 32 + ci) * 4104 + 4 + t0;
#pragma unroll
    for (int u = 0; u < 8; u += 2)
        *(float2*)(crow + u) = make_float2(lrelu(acc[u]), lrelu(acc[u + 1]));
    if (t0 == 0) crow[-1] = 0.f;        // guard cells for k_lvc phase-2
    if (t0 == 4088) crow[8] = 0.f;      // data[4096]
}

// ---------------- per-layer trio: cblock2 [0,1024) || pack [1024,1601) ||
// head2 [1601,1857). head reuses lx LDS storage (branch-exclusive).
template <int D>
__global__ __launch_bounds__(256) void
k_trio(const float* __restrict__ xx, const float* __restrict__ cb_ws,
       const float* __restrict__ cb_bs, float* __restrict__ cbp,
       const float* __restrict__ ker_w, const float* __restrict__ ker_b,
       ushort* __restrict__ Whi, ushort* __restrict__ Wlo, float* __restrict__ Bpk,
       const float* __restrict__ hp, const float* __restrict__ bias_w,
       const float* __restrict__ bias_b, float* __restrict__ kbL, int layer) {
    __shared__ float lx[32][132];
    __shared__ float wl[32][100];
    int blk = blockIdx.x;
    if (blk < 1024) {
        cblock2_body<D>(blk, threadIdx.x, xx, cb_ws, cb_bs, cbp, layer, lx, wl);
    } else if (blk < 1601) {
        pack_dev(blk - 1024, threadIdx.x, ker_w, ker_b, Whi, Wlo, Bpk, layer);
    } else {
        head2_body(blk - 1601, threadIdx.x, hp, bias_w, bias_b, kbL, layer,
                   &lx[0][0]);        // needs 2176 floats; lx has 4224
    }
}

// ---------------- fused: split-precision MFMA kernel-head GEMM + einsum + gate
// R29-EXACT CHUNK-PAIR (114us proven): pass processes chunks (c0, c0+1);
// kc[2][2048] single-buffered (LDS 40960, 4 blocks/CU); phase-2 loads xv once
// for both chunks. All chains order-identical to R21 -> bit-identical.
__global__ __launch_bounds__(256) void
k_lvc(const float* __restrict__ h, const float* __restrict__ cbp,
      const float* __restrict__ kbL, const ushort* __restrict__ Whi,
      const ushort* __restrict__ Wlo, const float* __restrict__ Bpk,
      float* __restrict__ xx) {
    __shared__ ushort HfH[6144];        // 12288 B: ((nt*6+ks)*64+lane)*8+j
    __shared__ ushort HfL[6144];        // 12288 B
    __shared__ float kc[2 * 2048];      // 16384 B: kc[u][...] for chunk pair
    // total 40960 B -> 4 blocks/CU

    int tid = threadIdx.x;
    // bijective remap: XCD = blockIdx%8 shared by the 4 qtr of group g.
    int g = (blockIdx.x >> 5) * 8 + (blockIdx.x & 7);   // (b,lt) group in [0,256)
    int qtr = (blockIdx.x >> 3) & 3;
    int lt = g & 15;
    int b = g >> 4;
    int l0 = lt * 32;

    // ---- build h hi/lo B-fragments ONCE into LDS (flat fragment order).
    for (int v = tid; v < 6144; v += 256) {
        int j = v & 7;
        int lane_ = (v >> 3) & 63;
        int r2 = v >> 9;                // nt_*6 + ks
        int ks = r2 % 6, nt_ = r2 / 6;
        int n = nt_ * 16 + (lane_ & 15);
        int cj = ks * 32 + (lane_ >> 4) * 8 + j;
        int ci = cj / 3, jt = cj - ci * 3;
        int p = l0 + n + jt - 1;
        float val = h[(size_t)(b * 64 + ci) * 520 + 4 + p];   // padded, p in [-1,512]
        ushort hi = f2bf(val);
        HfH[v] = hi;
        HfL[v] = f2bf(val - bf2f(hi));
    }
    __syncthreads();

    int wave = tid >> 6, lane = tid & 63;
    int n16 = lane & 15, quad = lane >> 4;
    int nt = wave & 1;                  // this wave's n-tile
    int mt0 = (wave >> 1) * 2;          // this wave's 2 local m-tiles

    const ushort* hfh = &HfH[(nt * 6) * 512 + lane * 8];
    const ushort* hfl = &HfL[(nt * 6) * 512 + lane * 8];

    int h8 = tid & 7, n2 = tid >> 3;    // phase-2: hop h8, location n2 in [0,32)
    int lg = l0 + n2;
    int tglob = lg * 8 + h8;
    const float* cbb = cbp + (size_t)b * 32 * 4104;
    const float* kbb = kbL + b * 64 * 512;
    float* xxb = xx + b * 32 * 4096;

    for (int hh = 0; hh < 2; ++hh) {
        int c0 = qtr * 4 + 2 * hh;      // chunk pair (c0, c0+1)
        f32x2 A01_0 = {0.f, 0.f}, A23_0 = {0.f, 0.f};
        f32x2 A01_1 = {0.f, 0.f}, A23_1 = {0.f, 0.f};
        for (int p = 0; p < 6; ++p) {
            // ---- phase 1: both chunks' MT jobs (independent chains; loads of
            // u=1 overlap MFMAs of u=0). Per-chunk body identical to R21.
#pragma unroll
            for (int u = 0; u < 2; ++u) {
                int c = c0 + u;
                int MT0 = p * 4 + mt0;
                const ushort* wh0 = Whi + (((size_t)(c * 24 + MT0) * 6) * 64 + lane) * 8;
                const ushort* wl0 = Wlo + (((size_t)(c * 24 + MT0) * 6) * 64 + lane) * 8;
                f32x4 acc0 = {0.f, 0.f, 0.f, 0.f};
                f32x4 acc1 = {0.f, 0.f, 0.f, 0.f};
                __builtin_amdgcn_s_setprio(1);
#pragma unroll 2
                for (int ks = 0; ks < 6; ++ks) {
                    short8 bhf = *reinterpret_cast<const short8*>(hfh + ks * 512);
                    short8 blf = *reinterpret_cast<const short8*>(hfl + ks * 512);
                    short8 w0h = *reinterpret_cast<const short8*>(wh0 + ks * 512);
                    short8 w0l = *reinterpret_cast<const short8*>(wl0 + ks * 512);
                    acc0 = __builtin_amdgcn_mfma_f32_16x16x32_bf16(w0h, bhf, acc0, 0, 0, 0);
                    acc0 = __builtin_amdgcn_mfma_f32_16x16x32_bf16(w0l, bhf, acc0, 0, 0, 0);
                    acc0 = __builtin_amdgcn_mfma_f32_16x16x32_bf16(w0h, blf, acc0, 0, 0, 0);
                    short8 w1h = *reinterpret_cast<const short8*>(wh0 + 3072 + ks * 512);
                    short8 w1l = *reinterpret_cast<const short8*>(wl0 + 3072 + ks * 512);
                    acc1 = __builtin_amdgcn_mfma_f32_16x16x32_bf16(w1h, bhf, acc1, 0, 0, 0);
                    acc1 = __builtin_amdgcn_mfma_f32_16x16x32_bf16(w1l, bhf, acc1, 0, 0, 0);
                    acc1 = __builtin_amdgcn_mfma_f32_16x16x32_bf16(w1h, blf, acc1, 0, 0, 0);
                }
                __builtin_amdgcn_s_setprio(0);
                acc0 += *reinterpret_cast<const f32x4*>(Bpk + c * 384 + MT0 * 16 + quad * 4);
                acc1 += *reinterpret_cast<const f32x4*>(Bpk + c * 384 + (MT0 + 1) * 16 + quad * 4);
                // D: col=lane&15 -> n16, row=quad*4+reg; ik_local = lmt*4+quad, oc=reg
                *reinterpret_cast<f32x4*>(
                    &kc[u * 2048 + ((mt0 * 4 + quad) * 32 + nt * 16 + n16) * 4]) = acc0;
                *reinterpret_cast<f32x4*>(
                    &kc[u * 2048 + (((mt0 + 1) * 4 + quad) * 32 + nt * 16 + n16) * 4]) = acc1;
            }
            __syncthreads();            // kc(p) complete for both chunks

            // ---- phase 2 partial: xv loaded ONCE, feeds both chunks' chains.
#pragma unroll
            for (int ikk = 0; ikk < 16; ++ikk) {
                int ik = p * 16 + ikk;
                int i = ik / 3, kk = ik - i * 3;
                float xv = cbb[(size_t)i * 4104 + 3 + tglob + kk];
                f32x2 xv2 = {xv, xv};
                float4 kv0 = *reinterpret_cast<const float4*>(&kc[(ikk * 32 + n2) * 4]);
                float4 kv1 = *reinterpret_cast<const float4*>(&kc[2048 + (ikk * 32 + n2) * 4]);
                f32x2 klo0 = {kv0.x, kv0.y}, khi0 = {kv0.z, kv0.w};
                f32x2 klo1 = {kv1.x, kv1.y}, khi1 = {kv1.z, kv1.w};
                A01_0 = __builtin_elementwise_fma(klo0, xv2, A01_0);
                A23_0 = __builtin_elementwise_fma(khi0, xv2, A23_0);
                A01_1 = __builtin_elementwise_fma(klo1, xv2, A01_1);
                A23_1 = __builtin_elementwise_fma(khi1, xv2, A23_1);
            }
            __syncthreads();            // kc consumed; next phase-1 may overwrite
        }
        // ---- gate both chunks: oc {0,1,2,3} -> o {2c, 32+2c, 2c+1, 32+2c+1}
        {
            int c = c0;
            float pa = A01_0.x + kbb[(2 * c) * 512 + lg];
            float pb = A01_0.y + kbb[(32 + 2 * c) * 512 + lg];
            float g2 = (1.f / (1.f + expf(-pa))) * tanhf(pb);
            xxb[(2 * c) * 4096 + tglob] += g2;
            pa = A23_0.x + kbb[(2 * c + 1) * 512 + lg];
            pb = A23_0.y + kbb[(32 + 2 * c + 1) * 512 + lg];
            g2 = (1.f / (1.f + expf(-pa))) * tanhf(pb);
            xxb[(2 * c + 1) * 4096 + tglob] += g2;
            c = c0 + 1;
            pa = A01_1.x + kbb[(2 * c) * 512 + lg];
            pb = A01_1.y + kbb[(32 + 2 * c) * 512 + lg];
            g2 = (1.f / (1.f + expf(-pa))) * tanhf(pb);
            xxb[(2 * c) * 4096 + tglob] += g2;
            pa = A23_1.x + kbb[(2 * c + 1) * 512 + lg];
            pb = A23_1.y + kbb[(32 + 2 * c + 1) * 512 + lg];
            g2 = (1.f / (1.f + expf(-pa))) * tanhf(pb);
            xxb[(2 * c + 1) * 4096 + tglob] += g2;
        }
    }
}

extern "C" void kernel_launch(void* const* d_in, const int* in_sizes, int n_in,
                              void* d_out, int out_size, void* d_ws, size_t ws_size,
                              hipStream_t stream) {
    const float* x      = (const float*)d_in[0];
    const float* c      = (const float*)d_in[1];
    const float* in_w   = (const float*)d_in[2];
    const float* in_b   = (const float*)d_in[3];
    const float* res_ws = (const float*)d_in[4];
    const float* res_bs = (const float*)d_in[5];
    const float* ker_w  = (const float*)d_in[6];
    const float* ker_b  = (const float*)d_in[7];
    const float* bias_w = (const float*)d_in[8];
    const float* bias_b = (const float*)d_in[9];
    const float* ct_w   = (const float*)d_in[10];
    const float* ct_b   = (const float*)d_in[11];
    const float* cb_ws  = (const float*)d_in[12];
    const float* cb_bs  = (const float*)d_in[13];

    float* ws   = (float*)d_ws;
    float* hp   = ws;                         // [0, 532480)       16*64*520 padded
    float* kbL  = ws + 532480;                // [532480, 1056768) 16*64*512
    float* tmp  = ws + 1056768;               // [1056768, 1589248) padded
    float* cbp  = ws + 1589248;               // [1589248, 3690496) 16*32*4104 padded
    ushort* Whi = (ushort*)(ws + 3690496);    // [3690496, 4280320)
    ushort* Wlo = (ushort*)(ws + 4280320);    // [4280320, 4870144)
    float* Bpk  = ws + 4870144;               // [4870144, 4876288)
    // high-water 19.51 MB (< 20.97 MB proven by R2's pass)
    float* xx   = (float*)d_out;              // state tensor lives in d_out

    k_fused_pc<<<740, 576, 0, stream>>>(c, in_w, in_b, hp, x, ct_w, ct_b, xx);
    for (int j = 0; j < 3; ++j) {
        k_res2<<<256, 256, 0, stream>>>(hp,  res_ws + (j * 2 + 0) * 64 * 64 * 3,
                                        res_bs + (j * 2 + 0) * 64, tmp, nullptr);
        k_res2<<<256, 256, 0, stream>>>(tmp, res_ws + (j * 2 + 1) * 64 * 64 * 3,
                                        res_bs + (j * 2 + 1) * 64, hp, hp);
    }

    for (int L = 0; L < 4; ++L) {
        switch (L) {
            case 0: k_trio<1><<<1857, 256, 0, stream>>>(xx, cb_ws, cb_bs, cbp,
                        ker_w, ker_b, Whi, Wlo, Bpk, hp, bias_w, bias_b, kbL, L); break;
            case 1: k_trio<3><<<1857, 256, 0, stream>>>(xx, cb_ws, cb_bs, cbp,
                        ker_w, ker_b, Whi, Wlo, Bpk, hp, bias_w, bias_b, kbL, L); break;
            case 2: k_trio<9><<<1857, 256, 0, stream>>>(xx, cb_ws, cb_bs, cbp,
                        ker_w, ker_b, Whi, Wlo, Bpk, hp, bias_w, bias_b, kbL, L); break;
            case 3: k_trio<27><<<1857, 256, 0, stream>>>(xx, cb_ws, cb_bs, cbp,
                        ker_w, ker_b, Whi, Wlo, Bpk, hp, bias_w, bias_b, kbL, L); break;
        }
        k_lvc<<<1024, 256, 0, stream>>>(hp, cbp, kbL, Whi, Wlo, Bpk, xx);
    }
}